// Round 2
// baseline (477.903 us; speedup 1.0000x reference)
//
#include <hip/hip_runtime.h>
#include <stdint.h>

typedef __attribute__((ext_vector_type(8))) short bf16x8;
typedef __attribute__((ext_vector_type(4))) short s16x4;
typedef __attribute__((ext_vector_type(4))) float f32x4;

#define DEVI __device__ __forceinline__

constexpr int B_ = 4, S_ = 2048, D_ = 1024, H_ = 16, DK_ = 64;
constexpr int M_ = B_ * S_;  // 8192 rows total

DEVI short f2bf(float f) {
  union { float f; uint32_t u; } x; x.f = f;
  uint32_t r = x.u + 0x7fffu + ((x.u >> 16) & 1u);  // RNE
  return (short)(uint16_t)(r >> 16);
}
DEVI float exp2_hw(float x) {  // v_exp_f32 is 2^x
  float r; asm("v_exp_f32 %0, %1" : "=v"(r) : "v"(x)); return r;
}

// ---------------- fp32 -> bf16 conversion ------------------------------------
__global__ __launch_bounds__(256) void cvt_f32_bf16(const float* __restrict__ in,
                                                    short* __restrict__ out, int n) {
  const int stride = gridDim.x * blockDim.x;
  const int ng = n >> 3;
  for (int g = blockIdx.x * blockDim.x + threadIdx.x; g < ng; g += stride) {
    const f32x4 a = *(const f32x4*)(in + (size_t)g * 8);
    const f32x4 b = *(const f32x4*)(in + (size_t)g * 8 + 4);
    bf16x8 o;
#pragma unroll
    for (int e = 0; e < 4; ++e) { o[e] = f2bf(a[e]); o[e + 4] = f2bf(b[e]); }
    *(bf16x8*)(out + (size_t)g * 8) = o;
  }
}

// ---------------- bf16 GEMM: C[m,n] = (sum_k A[m,k]*W[n,k] + bias)*scale ------
// MODE 0: bf16 row-major out. MODE 1: f32 row-major out.
// MODE 2: bf16 out transposed into Vt[(b*1024+n)][s] (s = m % 2048), rows S_.
template <int MODE>
__global__ __launch_bounds__(256) void gemm_bt(const short* __restrict__ A,
                                               const short* __restrict__ Bw,
                                               const float* __restrict__ bias,
                                               void* __restrict__ Cout,
                                               int Kdim, int Ndim, float scale) {
  __shared__ short sA[128 * 32];
  __shared__ short sB[128 * 32];
  const int tid = threadIdx.x;
  const int wid = tid >> 6, lane = tid & 63;
  const int m0 = blockIdx.x * 128, n0 = blockIdx.y * 128;
  const int wm = wid >> 1, wn = wid & 1;

  f32x4 acc[4][4];
#pragma unroll
  for (int i = 0; i < 4; ++i)
#pragma unroll
    for (int j = 0; j < 4; ++j) acc[i][j] = (f32x4){0.f, 0.f, 0.f, 0.f};

  const int srow = wid * 32 + (lane >> 2);
  const int scol = (lane & 3) * 8;
  const short* gA = A + (size_t)(m0 + srow) * Kdim + scol;
  const short* gB = Bw + (size_t)(n0 + srow) * Kdim + scol;
  short* lA0 = &sA[(wid * 32 + 0) * 32];
  short* lA1 = &sA[(wid * 32 + 16) * 32];
  short* lB0 = &sB[(wid * 32 + 0) * 32];
  short* lB1 = &sB[(wid * 32 + 16) * 32];

  for (int kt = 0; kt < Kdim; kt += 32) {
    __syncthreads();
    __builtin_amdgcn_global_load_lds(
        (const __attribute__((address_space(1))) uint32_t*)(gA + kt),
        (__attribute__((address_space(3))) uint32_t*)lA0, 16, 0, 0);
    __builtin_amdgcn_global_load_lds(
        (const __attribute__((address_space(1))) uint32_t*)(gA + (size_t)16 * Kdim + kt),
        (__attribute__((address_space(3))) uint32_t*)lA1, 16, 0, 0);
    __builtin_amdgcn_global_load_lds(
        (const __attribute__((address_space(1))) uint32_t*)(gB + kt),
        (__attribute__((address_space(3))) uint32_t*)lB0, 16, 0, 0);
    __builtin_amdgcn_global_load_lds(
        (const __attribute__((address_space(1))) uint32_t*)(gB + (size_t)16 * Kdim + kt),
        (__attribute__((address_space(3))) uint32_t*)lB1, 16, 0, 0);
    asm volatile("s_waitcnt vmcnt(0)" ::: "memory");
    __syncthreads();

    bf16x8 af[4], bfr[4];
#pragma unroll
    for (int mf = 0; mf < 4; ++mf)
      af[mf] = *(const bf16x8*)&sA[(wm * 64 + mf * 16 + (lane & 15)) * 32 + ((lane >> 4) * 8)];
#pragma unroll
    for (int nf = 0; nf < 4; ++nf)
      bfr[nf] = *(const bf16x8*)&sB[(wn * 64 + nf * 16 + (lane & 15)) * 32 + ((lane >> 4) * 8)];
#pragma unroll
    for (int mf = 0; mf < 4; ++mf)
#pragma unroll
      for (int nf = 0; nf < 4; ++nf)
        acc[mf][nf] = __builtin_amdgcn_mfma_f32_16x16x32_bf16(af[mf], bfr[nf], acc[mf][nf], 0, 0, 0);
  }

#pragma unroll
  for (int mf = 0; mf < 4; ++mf) {
#pragma unroll
    for (int nf = 0; nf < 4; ++nf) {
      const int n = n0 + wn * 64 + nf * 16 + (lane & 15);
      const float bi = bias[n];
      if (MODE == 2) {
        const int m_base = m0 + wm * 64 + mf * 16 + ((lane >> 4) * 4);
        const int b = m_base >> 11, s0 = m_base & 2047;
        s16x4 pk;
#pragma unroll
        for (int r = 0; r < 4; ++r) pk[r] = f2bf(acc[mf][nf][r] + bi);
        *(s16x4*)((short*)Cout + ((size_t)(b * 1024 + n)) * 2048 + s0) = pk;
      } else {
#pragma unroll
        for (int r = 0; r < 4; ++r) {
          const int m = m0 + wm * 64 + mf * 16 + ((lane >> 4) * 4) + r;
          const float vv = (acc[mf][nf][r] + bi) * scale;
          if (MODE == 0)
            ((short*)Cout)[(size_t)m * Ndim + n] = f2bf(vv);
          else
            ((float*)Cout)[(size_t)m * Ndim + n] = vv;
        }
      }
    }
  }
}

// ---------------- causal flash attention --------------------------------------
// QBLK=128 (4 waves x 32 q-rows), KVBLK=64. K and Vt staged via global_load_lds
// with pre-swizzled global source (XOR chunk swizzle), P round-trips through
// swizzled bf16 LDS. Softmax in base-2 domain (log2e folded into Q projection).
__global__ __launch_bounds__(256, 4) void attn_fwd(const short* __restrict__ Qf,
                                                   const short* __restrict__ Kf,
                                                   const short* __restrict__ Vt,
                                                   short* __restrict__ AO) {
  __shared__ short sK[64 * 64];   // [key][d], 128B rows, XOR-swizzled chunks
  __shared__ short sV[64 * 64];   // [d][key], 128B rows, XOR-swizzled chunks
  __shared__ short sP[4][32 * 64];// per-wave P (bf16), swizzled

  const int tid = threadIdx.x, wid = tid >> 6, lane = tid & 63;
  // bijective XCD swizzle (1024 % 8 == 0) + heavy-block-first
  const int cpx = gridDim.x >> 3;
  const int wg = (blockIdx.x & 7) * cpx + (blockIdx.x >> 3);
  const int bh = wg >> 4;
  const int bx = 15 - (wg & 15);
  const int b = bh >> 4, h = bh & 15;
  const int q0 = bx * 128;
  const int qw = q0 + wid * 32;
  const size_t rowbase = (size_t)b * S_ * D_ + (size_t)h * DK_;
  const size_t vbase = (size_t)bh * 64 * S_;

  // Q fragments (rows qw + rf*16 + (lane&15), already scaled by 1/8*log2e)
  bf16x8 aQ[2][2];
#pragma unroll
  for (int rf = 0; rf < 2; ++rf) {
    const short* qp = Qf + rowbase + (size_t)(qw + rf * 16 + (lane & 15)) * D_ + ((lane >> 4) * 8);
    aQ[rf][0] = *(const bf16x8*)qp;
    aQ[rf][1] = *(const bf16x8*)(qp + 32);
  }

  float m_run[2][4], lsum[2][4];
  f32x4 o[2][4];
#pragma unroll
  for (int rf = 0; rf < 2; ++rf)
#pragma unroll
    for (int r = 0; r < 4; ++r) { m_run[rf][r] = -1e30f; lsum[rf][r] = 0.f; }
#pragma unroll
  for (int rf = 0; rf < 2; ++rf)
#pragma unroll
    for (int nf = 0; nf < 4; ++nf) o[rf][nf] = (f32x4){0.f, 0.f, 0.f, 0.f};

  // staging mapping: per issue, 8 rows x 8 chunks; source chunk pre-swizzled
  const int srow = lane >> 3;                    // row within 8-row group
  const int schunk = (lane & 7) ^ srow;          // global chunk to fetch

  const int ntiles = bx * 2 + 2;
  for (int t = 0; t < ntiles; ++t) {
    const int kt = t * 64;
    __syncthreads();
#pragma unroll
    for (int j = 0; j < 2; ++j) {
      const int row = wid * 16 + j * 8;
      const short* gK = Kf + rowbase + (size_t)(kt + row + srow) * D_ + schunk * 8;
      __builtin_amdgcn_global_load_lds(
          (const __attribute__((address_space(1))) uint32_t*)gK,
          (__attribute__((address_space(3))) uint32_t*)&sK[row * 64], 16, 0, 0);
      const short* gV = Vt + vbase + (size_t)(row + srow) * S_ + kt + schunk * 8;
      __builtin_amdgcn_global_load_lds(
          (const __attribute__((address_space(1))) uint32_t*)gV,
          (__attribute__((address_space(3))) uint32_t*)&sV[row * 64], 16, 0, 0);
    }
    asm volatile("s_waitcnt vmcnt(0)" ::: "memory");
    __syncthreads();

    if (kt <= qw + 31) {  // wave has at least one unmasked column
      // ---- QK^T ----
      f32x4 p[2][4];
#pragma unroll
      for (int rf = 0; rf < 2; ++rf)
#pragma unroll
        for (int nf = 0; nf < 4; ++nf) p[rf][nf] = (f32x4){0.f, 0.f, 0.f, 0.f};
#pragma unroll
      for (int nf = 0; nf < 4; ++nf) {
        const int krow = nf * 16 + (lane & 15);
#pragma unroll
        for (int ks = 0; ks < 2; ++ks) {
          const int c = ks * 4 + (lane >> 4);
          bf16x8 bK = *(const bf16x8*)&sK[krow * 64 + ((c ^ (krow & 7)) << 3)];
#pragma unroll
          for (int rf = 0; rf < 2; ++rf)
            p[rf][nf] = __builtin_amdgcn_mfma_f32_16x16x32_bf16(aQ[rf][ks], bK, p[rf][nf], 0, 0, 0);
        }
      }
      // ---- causal mask (diag-overlapping tiles only) ----
      if (kt + 63 > qw) {
#pragma unroll
        for (int rf = 0; rf < 2; ++rf)
#pragma unroll
          for (int nf = 0; nf < 4; ++nf) {
            const int col = kt + nf * 16 + (lane & 15);
#pragma unroll
            for (int r = 0; r < 4; ++r) {
              const int row = qw + rf * 16 + ((lane >> 4) * 4) + r;
              if (col > row) p[rf][nf][r] = -1e30f;
            }
          }
      }
      // ---- online softmax (base-2) ----
#pragma unroll
      for (int rf = 0; rf < 2; ++rf)
#pragma unroll
        for (int r = 0; r < 4; ++r) {
          float mx = fmaxf(fmaxf(p[rf][0][r], p[rf][1][r]), fmaxf(p[rf][2][r], p[rf][3][r]));
          mx = fmaxf(mx, __shfl_xor(mx, 1));
          mx = fmaxf(mx, __shfl_xor(mx, 2));
          mx = fmaxf(mx, __shfl_xor(mx, 4));
          mx = fmaxf(mx, __shfl_xor(mx, 8));
          const float mnew = fmaxf(m_run[rf][r], mx);
          const float corr = exp2_hw(m_run[rf][r] - mnew);
          float rs = 0.f;
#pragma unroll
          for (int nf = 0; nf < 4; ++nf) {
            const float pe = exp2_hw(p[rf][nf][r] - mnew);
            p[rf][nf][r] = pe;
            rs += pe;
          }
          rs += __shfl_xor(rs, 1);
          rs += __shfl_xor(rs, 2);
          rs += __shfl_xor(rs, 4);
          rs += __shfl_xor(rs, 8);
          lsum[rf][r] = lsum[rf][r] * corr + rs;
          m_run[rf][r] = mnew;
#pragma unroll
          for (int nf = 0; nf < 4; ++nf) o[rf][nf][r] *= corr;
        }
      // ---- P -> LDS (bf16, swizzled) ----
      short* pw = &sP[wid][0];
#pragma unroll
      for (int rf = 0; rf < 2; ++rf)
#pragma unroll
        for (int nf = 0; nf < 4; ++nf) {
          const int chunk = nf * 2 + ((lane & 15) >> 3);
#pragma unroll
          for (int r = 0; r < 4; ++r) {
            const int rloc = rf * 16 + ((lane >> 4) * 4) + r;
            pw[rloc * 64 + ((chunk ^ (rloc & 7)) << 3) + (lane & 7)] = f2bf(p[rf][nf][r]);
          }
        }
      asm volatile("s_waitcnt lgkmcnt(0)" ::: "memory");
      // ---- PV ----
#pragma unroll
      for (int ks = 0; ks < 2; ++ks) {
        const int c = ks * 4 + (lane >> 4);
        bf16x8 aP[2];
#pragma unroll
        for (int rf = 0; rf < 2; ++rf) {
          const int rloc = rf * 16 + (lane & 15);
          aP[rf] = *(const bf16x8*)&pw[rloc * 64 + ((c ^ (rloc & 7)) << 3)];
        }
#pragma unroll
        for (int nf = 0; nf < 4; ++nf) {
          const int vrow = nf * 16 + (lane & 15);
          bf16x8 bV = *(const bf16x8*)&sV[vrow * 64 + ((c ^ (vrow & 7)) << 3)];
#pragma unroll
          for (int rf = 0; rf < 2; ++rf)
            o[rf][nf] = __builtin_amdgcn_mfma_f32_16x16x32_bf16(aP[rf], bV, o[rf][nf], 0, 0, 0);
        }
      }
    }
  }

  // finalize
#pragma unroll
  for (int rf = 0; rf < 2; ++rf) {
    float inv[4];
#pragma unroll
    for (int r = 0; r < 4; ++r) inv[r] = 1.f / lsum[rf][r];
#pragma unroll
    for (int nf = 0; nf < 4; ++nf)
#pragma unroll
      for (int r = 0; r < 4; ++r) {
        const int row = qw + rf * 16 + ((lane >> 4) * 4) + r;
        AO[rowbase + (size_t)row * D_ + nf * 16 + (lane & 15)] = f2bf(o[rf][nf][r] * inv[r]);
      }
  }
}

// ---------------- launch -------------------------------------------------------
extern "C" void kernel_launch(void* const* d_in, const int* in_sizes, int n_in,
                              void* d_out, int out_size, void* d_ws, size_t ws_size,
                              hipStream_t stream) {
  (void)in_sizes; (void)n_in; (void)out_size; (void)ws_size;
  const float* q  = (const float*)d_in[0];
  const float* k  = (const float*)d_in[1];
  const float* v  = (const float*)d_in[2];
  const float* Wq = (const float*)d_in[4];
  const float* bq = (const float*)d_in[5];
  const float* Wk = (const float*)d_in[6];
  const float* bk = (const float*)d_in[7];
  const float* Wv = (const float*)d_in[8];
  const float* bv = (const float*)d_in[9];
  const float* Wo = (const float*)d_in[10];
  const float* bo = (const float*)d_in[11];

  char* ws = (char*)d_ws;
  const size_t MB = 1ull << 20;
  short* wqb = (short*)(ws + 0 * MB);
  short* wkb = (short*)(ws + 2 * MB);
  short* wvb = (short*)(ws + 4 * MB);
  short* wob = (short*)(ws + 6 * MB);
  short* Qf  = (short*)(ws + 8 * MB);
  short* Kf  = (short*)(ws + 24 * MB);
  short* Vtb = (short*)(ws + 40 * MB);  // transposed V: [(b*1024+n)][s]
  short* xq  = (short*)(ws + 56 * MB);
  short* xk  = (short*)(ws + 72 * MB);
  short* xv  = (short*)(ws + 88 * MB);
  short* AO  = xq;

  const int BSD = B_ * S_ * D_;
  cvt_f32_bf16<<<4096, 256, 0, stream>>>(q, xq, BSD);
  cvt_f32_bf16<<<4096, 256, 0, stream>>>(k, xk, BSD);
  cvt_f32_bf16<<<4096, 256, 0, stream>>>(v, xv, BSD);
  cvt_f32_bf16<<<512, 256, 0, stream>>>(Wq, wqb, D_ * D_);
  cvt_f32_bf16<<<512, 256, 0, stream>>>(Wk, wkb, D_ * D_);
  cvt_f32_bf16<<<512, 256, 0, stream>>>(Wv, wvb, D_ * D_);
  cvt_f32_bf16<<<512, 256, 0, stream>>>(Wo, wob, D_ * D_);

  dim3 gg(M_ / 128, D_ / 128);
  // Q projection folds 1/sqrt(DK) * log2(e) so softmax runs in base-2
  gemm_bt<0><<<gg, 256, 0, stream>>>(xq, wqb, bq, Qf, D_, D_, 0.125f * 1.4426950408889634f);
  gemm_bt<0><<<gg, 256, 0, stream>>>(xk, wkb, bk, Kf, D_, D_, 1.0f);
  gemm_bt<2><<<gg, 256, 0, stream>>>(xv, wvb, bv, Vtb, D_, D_, 1.0f);

  attn_fwd<<<dim3((S_ / 128) * B_ * H_), 256, 0, stream>>>(Qf, Kf, Vtb, AO);

  gemm_bt<1><<<gg, 256, 0, stream>>>(AO, wob, bo, d_out, D_, D_, 1.0f);
}

// Round 3
// 245.369 us; speedup vs baseline: 1.9477x; 1.9477x over previous
//
#include <hip/hip_runtime.h>
#include <stdint.h>

typedef __attribute__((ext_vector_type(8))) short bf16x8;
typedef __attribute__((ext_vector_type(4))) short s16x4;
typedef __attribute__((ext_vector_type(4))) float f32x4;
typedef __attribute__((ext_vector_type(16))) float f32x16;

#define DEVI __device__ __forceinline__

constexpr int B_ = 4, S_ = 2048, D_ = 1024, H_ = 16, DK_ = 64;
constexpr int M_ = B_ * S_;  // 8192 rows total

DEVI short f2bf(float f) {
  union { float f; uint32_t u; } x; x.f = f;
  uint32_t r = x.u + 0x7fffu + ((x.u >> 16) & 1u);  // RNE
  return (short)(uint16_t)(r >> 16);
}
DEVI float exp2_hw(float x) {  // v_exp_f32 is 2^x
  float r; asm("v_exp_f32 %0, %1" : "=v"(r) : "v"(x)); return r;
}
DEVI uint32_t cvtpk(float lo, float hi) {  // [15:0]=bf16(lo), [31:16]=bf16(hi)
  uint32_t r; asm("v_cvt_pk_bf16_f32 %0, %1, %2" : "=v"(r) : "v"(lo), "v"(hi));
  return r;
}
DEVI void gload16(const short* g, short* l) {
  __builtin_amdgcn_global_load_lds((const __attribute__((address_space(1))) uint32_t*)g,
                                   (__attribute__((address_space(3))) uint32_t*)l, 16, 0, 0);
}

// ---------------- fp32 -> bf16 conversion ------------------------------------
__global__ __launch_bounds__(256) void cvt_f32_bf16(const float* __restrict__ in,
                                                    short* __restrict__ out, int n) {
  const int stride = gridDim.x * blockDim.x;
  const int ng = n >> 3;
  for (int g = blockIdx.x * blockDim.x + threadIdx.x; g < ng; g += stride) {
    const f32x4 a = *(const f32x4*)(in + (size_t)g * 8);
    const f32x4 b = *(const f32x4*)(in + (size_t)g * 8 + 4);
    bf16x8 o;
#pragma unroll
    for (int e = 0; e < 4; ++e) { o[e] = f2bf(a[e]); o[e + 4] = f2bf(b[e]); }
    *(bf16x8*)(out + (size_t)g * 8) = o;
  }
}

// ---------------- bf16 GEMM: C[m,n] = (sum_k A[m,k]*W[n,k] + bias)*scale ------
// MODE 0: bf16 row-major out. MODE 1: f32 row-major out.
// MODE 2: bf16 out transposed into Vt[(b*1024+n)][s] (s = m % 2048), rows S_.
template <int MODE>
__global__ __launch_bounds__(256) void gemm_bt(const short* __restrict__ A,
                                               const short* __restrict__ Bw,
                                               const float* __restrict__ bias,
                                               void* __restrict__ Cout,
                                               int Kdim, int Ndim, float scale) {
  __shared__ short sA[128 * 32];
  __shared__ short sB[128 * 32];
  const int tid = threadIdx.x;
  const int wid = tid >> 6, lane = tid & 63;
  const int m0 = blockIdx.x * 128, n0 = blockIdx.y * 128;
  const int wm = wid >> 1, wn = wid & 1;

  f32x4 acc[4][4];
#pragma unroll
  for (int i = 0; i < 4; ++i)
#pragma unroll
    for (int j = 0; j < 4; ++j) acc[i][j] = (f32x4){0.f, 0.f, 0.f, 0.f};

  const int srow = wid * 32 + (lane >> 2);
  const int scol = (lane & 3) * 8;
  const short* gA = A + (size_t)(m0 + srow) * Kdim + scol;
  const short* gB = Bw + (size_t)(n0 + srow) * Kdim + scol;
  short* lA0 = &sA[(wid * 32 + 0) * 32];
  short* lA1 = &sA[(wid * 32 + 16) * 32];
  short* lB0 = &sB[(wid * 32 + 0) * 32];
  short* lB1 = &sB[(wid * 32 + 16) * 32];

  for (int kt = 0; kt < Kdim; kt += 32) {
    __syncthreads();
    gload16(gA + kt, lA0);
    gload16(gA + (size_t)16 * Kdim + kt, lA1);
    gload16(gB + kt, lB0);
    gload16(gB + (size_t)16 * Kdim + kt, lB1);
    asm volatile("s_waitcnt vmcnt(0)" ::: "memory");
    __syncthreads();

    bf16x8 af[4], bfr[4];
#pragma unroll
    for (int mf = 0; mf < 4; ++mf)
      af[mf] = *(const bf16x8*)&sA[(wm * 64 + mf * 16 + (lane & 15)) * 32 + ((lane >> 4) * 8)];
#pragma unroll
    for (int nf = 0; nf < 4; ++nf)
      bfr[nf] = *(const bf16x8*)&sB[(wn * 64 + nf * 16 + (lane & 15)) * 32 + ((lane >> 4) * 8)];
#pragma unroll
    for (int mf = 0; mf < 4; ++mf)
#pragma unroll
      for (int nf = 0; nf < 4; ++nf)
        acc[mf][nf] = __builtin_amdgcn_mfma_f32_16x16x32_bf16(af[mf], bfr[nf], acc[mf][nf], 0, 0, 0);
  }

#pragma unroll
  for (int mf = 0; mf < 4; ++mf) {
#pragma unroll
    for (int nf = 0; nf < 4; ++nf) {
      const int n = n0 + wn * 64 + nf * 16 + (lane & 15);
      const float bi = bias[n];
      if (MODE == 2) {
        const int m_base = m0 + wm * 64 + mf * 16 + ((lane >> 4) * 4);
        const int b = m_base >> 11, s0 = m_base & 2047;
        s16x4 pk;
#pragma unroll
        for (int r = 0; r < 4; ++r) pk[r] = f2bf(acc[mf][nf][r] + bi);
        *(s16x4*)((short*)Cout + ((size_t)(b * 1024 + n)) * 2048 + s0) = pk;
      } else {
#pragma unroll
        for (int r = 0; r < 4; ++r) {
          const int m = m0 + wm * 64 + mf * 16 + ((lane >> 4) * 4) + r;
          const float vv = (acc[mf][nf][r] + bi) * scale;
          if (MODE == 0)
            ((short*)Cout)[(size_t)m * Ndim + n] = f2bf(vv);
          else
            ((float*)Cout)[(size_t)m * Ndim + n] = vv;
        }
      }
    }
  }
}

// ---------------- causal flash attention --------------------------------------
// 4 waves x 32 q-rows (QBLK=128), KVBLK=64, 32x32x16 MFMA, SWAPPED operands:
//   QK^T: D[key][q]  (lane owns ONE q = lane&31; keys split across lane-halves)
//   PV:   D[d][q]    (rescale lane-local)
// In-register softmax: local reduce + 2x shfl_xor(32). P->B-frag via cvt_pk +
// shfl_xor(32) exchange (no LDS round-trip). Double-buffered K/V staging with
// STAGE(t+1) issued before compute(t); one drain+barrier per tile.
__global__ __launch_bounds__(256, 3) void attn_fwd(const short* __restrict__ Qf,
                                                   const short* __restrict__ Kf,
                                                   const short* __restrict__ Vt,
                                                   short* __restrict__ AO) {
  __shared__ short sK[2][64 * 64];   // [key][d], swizzled chunks
  __shared__ short sV[2][64 * 64];   // [d][key], swizzled chunks

  const int tid = threadIdx.x, wid = tid >> 6, lane = tid & 63;
  const int h = lane >> 5, ql = lane & 31;
  // bijective XCD swizzle (gridDim.x % 8 == 0) + heavy-block-first
  const int cpx = gridDim.x >> 3;
  const int wg = (blockIdx.x & 7) * cpx + (blockIdx.x >> 3);
  const int bh = wg >> 4;
  const int bx = 15 - (wg & 15);
  const int b = bh >> 4, hd = bh & 15;
  const int qw = bx * 128 + wid * 32;
  const int qg = qw + ql;                      // this lane's q row
  const size_t rowbase = (size_t)b * S_ * D_ + (size_t)hd * DK_;
  const size_t vbase = (size_t)bh * 64 * S_;

  // Q fragments: B[q=qw+ql][d = dstep*16 + h*8 .. +8]  (scaled by 0.125*log2e)
  bf16x8 aQ[4];
  {
    const short* qp = Qf + rowbase + (size_t)qg * D_ + h * 8;
#pragma unroll
    for (int d = 0; d < 4; ++d) aQ[d] = *(const bf16x8*)(qp + d * 16);
  }

  f32x16 o0, o1;  // O[d = df*32 + 8(reg>>2)+4h+(reg&3)][q = qg]
#pragma unroll
  for (int i = 0; i < 16; ++i) { o0[i] = 0.f; o1[i] = 0.f; }
  float m_run = -1e30f, lsum = 0.f;

  // staging: 8-row groups; source chunk pre-swizzled so LDS[r][c]=g[r][c^(r&7)]
  const int srow = lane >> 3;
  const int schunk = ((lane & 7) ^ srow) * 8;
  const short* gK = Kf + rowbase + (size_t)(wid * 16 + srow) * D_ + schunk;
  const short* gV = Vt + vbase + (size_t)(wid * 16 + srow) * S_ + schunk;

  auto STAGE = [&](int bufi, int kt) {
    const short* gk = gK + (size_t)kt * D_;
    const short* gv = gV + kt;
    short* dk = &sK[bufi][(wid * 16) * 64];
    short* dv = &sV[bufi][(wid * 16) * 64];
    gload16(gk, dk);
    gload16(gk + (size_t)8 * D_, dk + 8 * 64);
    gload16(gv, dv);
    gload16(gv + (size_t)8 * S_, dv + 8 * 64);
  };

  const int nt = bx * 2 + 2;
  STAGE(0, 0);
  __syncthreads();  // prologue drain (vmcnt(0) implicit)
  int cur = 0;

  for (int t = 0; t < nt; ++t) {
    const int kt = t * 64;
    if (t + 1 < nt) STAGE(cur ^ 1, kt + 64);  // prefetch; drains at loop end
    if (kt <= qw + 31) {
      const short* bK = &sK[cur][0];
      const short* bV = &sV[cur][0];
      // ---- QK^T swapped: p[kf][reg] = P[key = kt+kf*32+8(reg>>2)+4h+(reg&3)][qg]
      f32x16 p0, p1;
#pragma unroll
      for (int i = 0; i < 16; ++i) { p0[i] = 0.f; p1[i] = 0.f; }
#pragma unroll
      for (int d = 0; d < 4; ++d) {
        const int c = d * 2 + h;
        const int r1 = 32 + ql;
        bf16x8 k0 = *(const bf16x8*)&bK[ql * 64 + ((c ^ (ql & 7)) << 3)];
        bf16x8 k1 = *(const bf16x8*)&bK[r1 * 64 + ((c ^ (r1 & 7)) << 3)];
        p0 = __builtin_amdgcn_mfma_f32_32x32x16_bf16(k0, aQ[d], p0, 0, 0, 0);
        p1 = __builtin_amdgcn_mfma_f32_32x32x16_bf16(k1, aQ[d], p1, 0, 0, 0);
      }
      // ---- causal mask (exactly one diagonal tile per wave) ----
      if (kt + 63 > qw) {
        const int qk = qg - kt;
#pragma unroll
        for (int i = 0; i < 16; ++i) {
          const int k0i = 8 * (i >> 2) + 4 * h + (i & 3);
          if (k0i > qk) p0[i] = -1e30f;
          if (k0i + 32 > qk) p1[i] = -1e30f;
        }
      }
      // ---- online softmax (base-2), lane-local q ----
      float mx = fmaxf(p0[0], p1[0]);
#pragma unroll
      for (int i = 1; i < 16; ++i) mx = fmaxf(mx, fmaxf(p0[i], p1[i]));
      mx = fmaxf(mx, __shfl_xor(mx, 32));
      const float mnew = fmaxf(m_run, mx);
      const float corr = exp2_hw(m_run - mnew);
      float rs = 0.f;
#pragma unroll
      for (int i = 0; i < 16; ++i) {
        p0[i] = exp2_hw(p0[i] - mnew); rs += p0[i];
        p1[i] = exp2_hw(p1[i] - mnew); rs += p1[i];
      }
      rs += __shfl_xor(rs, 32);
      lsum = lsum * corr + rs;
      m_run = mnew;
#pragma unroll
      for (int i = 0; i < 16; ++i) { o0[i] *= corr; o1[i] *= corr; }
      // ---- pack P to bf16 pairs: c[j]=keys{base,base+1}, d[j]=keys{base+2,+3}
      uint32_t cj[8], dj[8];  // j = kf*4 + (reg>>2); key base = 32kf+8(j&3)+4h
#pragma unroll
      for (int j = 0; j < 4; ++j) {
        cj[j]     = cvtpk(p0[4 * j], p0[4 * j + 1]);
        dj[j]     = cvtpk(p0[4 * j + 2], p0[4 * j + 3]);
        cj[4 + j] = cvtpk(p1[4 * j], p1[4 * j + 1]);
        dj[4 + j] = cvtpk(p1[4 * j + 2], p1[4 * j + 3]);
      }
      // ---- PV swapped: B-frag[m] = P[qg][keys 16m+8h..+7] via xor-32 exchange
#pragma unroll
      for (int m = 0; m < 4; ++m) {
        const uint32_t pc = h ? cj[2 * m] : cj[2 * m + 1];  // push what partner needs
        const uint32_t pd = h ? dj[2 * m] : dj[2 * m + 1];
        const uint32_t rc = (uint32_t)__shfl_xor((int)pc, 32);
        const uint32_t rd = (uint32_t)__shfl_xor((int)pd, 32);
        union { uint32_t w[4]; bf16x8 v; } u;
        u.w[0] = h ? rc : cj[2 * m];
        u.w[1] = h ? rd : dj[2 * m];
        u.w[2] = h ? cj[2 * m + 1] : rc;
        u.w[3] = h ? dj[2 * m + 1] : rd;
        const int cv = m * 2 + h;
        const int vr1 = 32 + ql;
        bf16x8 v0 = *(const bf16x8*)&bV[ql * 64 + ((cv ^ (ql & 7)) << 3)];
        bf16x8 v1 = *(const bf16x8*)&bV[vr1 * 64 + ((cv ^ (vr1 & 7)) << 3)];
        o0 = __builtin_amdgcn_mfma_f32_32x32x16_bf16(v0, u.v, o0, 0, 0, 0);
        o1 = __builtin_amdgcn_mfma_f32_32x32x16_bf16(v1, u.v, o1, 0, 0, 0);
      }
    }
    __syncthreads();  // drains vmcnt(0): tile t+1 landed; all done reading cur
    cur ^= 1;
  }

  // ---- epilogue: normalize, write bf16 rows (4 contiguous d per quad -> 8B) --
  const float invl = 1.f / lsum;
  short* op = AO + rowbase + (size_t)qg * D_;
#pragma unroll
  for (int j = 0; j < 4; ++j) {
    s16x4 w0, w1;
#pragma unroll
    for (int r = 0; r < 4; ++r) {
      w0[r] = f2bf(o0[4 * j + r] * invl);
      w1[r] = f2bf(o1[4 * j + r] * invl);
    }
    *(s16x4*)(op + 8 * j + 4 * h) = w0;
    *(s16x4*)(op + 32 + 8 * j + 4 * h) = w1;
  }
}

// ---------------- launch -------------------------------------------------------
extern "C" void kernel_launch(void* const* d_in, const int* in_sizes, int n_in,
                              void* d_out, int out_size, void* d_ws, size_t ws_size,
                              hipStream_t stream) {
  (void)in_sizes; (void)n_in; (void)out_size; (void)ws_size;
  const float* q  = (const float*)d_in[0];
  const float* k  = (const float*)d_in[1];
  const float* v  = (const float*)d_in[2];
  const float* Wq = (const float*)d_in[4];
  const float* bq = (const float*)d_in[5];
  const float* Wk = (const float*)d_in[6];
  const float* bk = (const float*)d_in[7];
  const float* Wv = (const float*)d_in[8];
  const float* bv = (const float*)d_in[9];
  const float* Wo = (const float*)d_in[10];
  const float* bo = (const float*)d_in[11];

  char* ws = (char*)d_ws;
  const size_t MB = 1ull << 20;
  short* wqb = (short*)(ws + 0 * MB);
  short* wkb = (short*)(ws + 2 * MB);
  short* wvb = (short*)(ws + 4 * MB);
  short* wob = (short*)(ws + 6 * MB);
  short* Qf  = (short*)(ws + 8 * MB);
  short* Kf  = (short*)(ws + 24 * MB);
  short* Vtb = (short*)(ws + 40 * MB);  // transposed V: [(b*1024+n)][s]
  short* xq  = (short*)(ws + 56 * MB);
  short* xk  = (short*)(ws + 72 * MB);
  short* xv  = (short*)(ws + 88 * MB);
  short* AO  = xq;

  const int BSD = B_ * S_ * D_;
  cvt_f32_bf16<<<4096, 256, 0, stream>>>(q, xq, BSD);
  cvt_f32_bf16<<<4096, 256, 0, stream>>>(k, xk, BSD);
  cvt_f32_bf16<<<4096, 256, 0, stream>>>(v, xv, BSD);
  cvt_f32_bf16<<<512, 256, 0, stream>>>(Wq, wqb, D_ * D_);
  cvt_f32_bf16<<<512, 256, 0, stream>>>(Wk, wkb, D_ * D_);
  cvt_f32_bf16<<<512, 256, 0, stream>>>(Wv, wvb, D_ * D_);
  cvt_f32_bf16<<<512, 256, 0, stream>>>(Wo, wob, D_ * D_);

  dim3 gg(M_ / 128, D_ / 128);
  // Q projection folds 1/sqrt(DK) * log2(e) so softmax runs in base-2
  gemm_bt<0><<<gg, 256, 0, stream>>>(xq, wqb, bq, Qf, D_, D_, 0.125f * 1.4426950408889634f);
  gemm_bt<0><<<gg, 256, 0, stream>>>(xk, wkb, bk, Kf, D_, D_, 1.0f);
  gemm_bt<2><<<gg, 256, 0, stream>>>(xv, wvb, bv, Vtb, D_, D_, 1.0f);

  attn_fwd<<<dim3((S_ / 128) * B_ * H_), 256, 0, stream>>>(Qf, Kf, Vtb, AO);

  gemm_bt<1><<<gg, 256, 0, stream>>>(AO, wob, bo, d_out, D_, D_, 1.0f);
}

// Round 4
// 213.401 us; speedup vs baseline: 2.2395x; 1.1498x over previous
//
#include <hip/hip_runtime.h>
#include <stdint.h>

typedef __attribute__((ext_vector_type(8))) short bf16x8;
typedef __attribute__((ext_vector_type(4))) short s16x4;
typedef __attribute__((ext_vector_type(4))) float f32x4;
typedef __attribute__((ext_vector_type(16))) float f32x16;

#define DEVI __device__ __forceinline__

constexpr int B_ = 4, S_ = 2048, D_ = 1024, H_ = 16, DK_ = 64;
constexpr int M_ = B_ * S_;  // 8192 rows total

DEVI short f2bf(float f) {
  union { float f; uint32_t u; } x; x.f = f;
  uint32_t r = x.u + 0x7fffu + ((x.u >> 16) & 1u);  // RNE
  return (short)(uint16_t)(r >> 16);
}
DEVI float exp2_hw(float x) {  // v_exp_f32 is 2^x
  float r; asm("v_exp_f32 %0, %1" : "=v"(r) : "v"(x)); return r;
}
DEVI uint32_t cvtpk(float lo, float hi) {  // [15:0]=bf16(lo), [31:16]=bf16(hi)
  uint32_t r; asm("v_cvt_pk_bf16_f32 %0, %1, %2" : "=v"(r) : "v"(lo), "v"(hi));
  return r;
}
DEVI void gload16(const short* g, short* l) {
  __builtin_amdgcn_global_load_lds((const __attribute__((address_space(1))) uint32_t*)g,
                                   (__attribute__((address_space(3))) uint32_t*)l, 16, 0, 0);
}

// ---------------- fp32 -> bf16 conversion ------------------------------------
__global__ __launch_bounds__(256) void cvt_f32_bf16(const float* __restrict__ in,
                                                    short* __restrict__ out, int n) {
  const int stride = gridDim.x * blockDim.x;
  const int ng = n >> 3;
  for (int g = blockIdx.x * blockDim.x + threadIdx.x; g < ng; g += stride) {
    const f32x4 a = *(const f32x4*)(in + (size_t)g * 8);
    const f32x4 b = *(const f32x4*)(in + (size_t)g * 8 + 4);
    bf16x8 o;
#pragma unroll
    for (int e = 0; e < 4; ++e) { o[e] = f2bf(a[e]); o[e + 4] = f2bf(b[e]); }
    *(bf16x8*)(out + (size_t)g * 8) = o;
  }
}

// ---------------- bf16 GEMM: C[m,n] = (sum_k A[m,k]*W[n,k] + bias)*scale ------
// 128x128 tile, BK=32, 4 waves, 16x16x32 MFMA. 2-phase dbuf (prefetch before
// compute, one barrier/iter) + XOR chunk swizzle (2-way bank spread).
// MODE 0: bf16 row-major out. MODE 1: f32 row-major out.
// MODE 2: bf16 out transposed into Vt[(b*1024+n)][s] (s = m % 2048), rows S_.
template <int MODE>
__global__ __launch_bounds__(256) void gemm_bt(const short* __restrict__ A,
                                               const short* __restrict__ Bw,
                                               const float* __restrict__ bias,
                                               void* __restrict__ Cout,
                                               int Kdim, int Ndim, float scale) {
  __shared__ short sA[2][128 * 32];
  __shared__ short sB[2][128 * 32];
  const int tid = threadIdx.x;
  const int wid = tid >> 6, lane = tid & 63;
  const int m0 = blockIdx.x * 128, n0 = blockIdx.y * 128;
  const int wm = wid >> 1, wn = wid & 1;

  f32x4 acc[4][4];
#pragma unroll
  for (int i = 0; i < 4; ++i)
#pragma unroll
    for (int j = 0; j < 4; ++j) acc[i][j] = (f32x4){0.f, 0.f, 0.f, 0.f};

  // staging: wave covers rows [wid*32, wid*32+32), 2 issues per operand.
  // LDS[r][c] = G[r][c ^ swz(r)], swz(r) = (r&3)^((r>>2)&3)  (same for r, r+16)
  const int srow = wid * 32 + (lane >> 2);
  const int swzs = (srow & 3) ^ ((srow >> 2) & 3);
  const int scol = ((lane & 3) ^ swzs) * 8;
  const short* gA = A + (size_t)(m0 + srow) * Kdim + scol;
  const short* gB = Bw + (size_t)(n0 + srow) * Kdim + scol;

  auto STAGE = [&](int bi, int kt) {
    short* la = &sA[bi][(wid * 32) * 32];
    short* lb = &sB[bi][(wid * 32) * 32];
    gload16(gA + kt, la);
    gload16(gA + (size_t)16 * Kdim + kt, la + 16 * 32);
    gload16(gB + kt, lb);
    gload16(gB + (size_t)16 * Kdim + kt, lb + 16 * 32);
  };

  STAGE(0, 0);
  __syncthreads();
  int cur = 0;

  // frag-read swizzle: row r = *+ (lane&15) -> swz(r) = (lane&3)^((lane>>2)&3)
  const int swzf = (lane & 3) ^ ((lane >> 2) & 3);
  const int cofs = (((lane >> 4) ^ swzf) << 3);

  for (int kt = 0; kt < Kdim; kt += 32) {
    if (kt + 32 < Kdim) STAGE(cur ^ 1, kt + 32);
    bf16x8 af[4], bfr[4];
#pragma unroll
    for (int mf = 0; mf < 4; ++mf)
      af[mf] = *(const bf16x8*)&sA[cur][(wm * 64 + mf * 16 + (lane & 15)) * 32 + cofs];
#pragma unroll
    for (int nf = 0; nf < 4; ++nf)
      bfr[nf] = *(const bf16x8*)&sB[cur][(wn * 64 + nf * 16 + (lane & 15)) * 32 + cofs];
#pragma unroll
    for (int mf = 0; mf < 4; ++mf)
#pragma unroll
      for (int nf = 0; nf < 4; ++nf)
        acc[mf][nf] = __builtin_amdgcn_mfma_f32_16x16x32_bf16(af[mf], bfr[nf], acc[mf][nf], 0, 0, 0);
    __syncthreads();  // drains vmcnt(0)+lgkmcnt(0): next tile landed, reads done
    cur ^= 1;
  }

#pragma unroll
  for (int mf = 0; mf < 4; ++mf) {
#pragma unroll
    for (int nf = 0; nf < 4; ++nf) {
      const int n = n0 + wn * 64 + nf * 16 + (lane & 15);
      const float bi = bias[n];
      if (MODE == 2) {
        const int m_base = m0 + wm * 64 + mf * 16 + ((lane >> 4) * 4);
        const int b = m_base >> 11, s0 = m_base & 2047;
        s16x4 pk;
#pragma unroll
        for (int r = 0; r < 4; ++r) pk[r] = f2bf(acc[mf][nf][r] + bi);
        *(s16x4*)((short*)Cout + ((size_t)(b * 1024 + n)) * 2048 + s0) = pk;
      } else {
#pragma unroll
        for (int r = 0; r < 4; ++r) {
          const int m = m0 + wm * 64 + mf * 16 + ((lane >> 4) * 4) + r;
          const float vv = (acc[mf][nf][r] + bi) * scale;
          if (MODE == 0)
            ((short*)Cout)[(size_t)m * Ndim + n] = f2bf(vv);
          else
            ((float*)Cout)[(size_t)m * Ndim + n] = vv;
        }
      }
    }
  }
}

// ---------------- causal flash attention --------------------------------------
// 8 waves x 32 q-rows. Causal load-pairing: waves 0-3 -> q-panel (15-pi),
// waves 4-7 -> q-panel pi  => uniform 34 wave-tiles per block, K/V staged once
// for all 8 waves. 32x32x16 MFMA, swapped operands, in-register softmax with
// defer-max (T13), setprio around MFMA clusters (T5), 2-phase dbuf staging.
__global__ __launch_bounds__(512, 4) void attn_fwd(const short* __restrict__ Qf,
                                                   const short* __restrict__ Kf,
                                                   const short* __restrict__ Vt,
                                                   short* __restrict__ AO) {
  __shared__ short sK[2][64 * 64];   // [key][d], swizzled chunks
  __shared__ short sV[2][64 * 64];   // [d][key], swizzled chunks

  const int tid = threadIdx.x, wid = tid >> 6, lane = tid & 63;
  const int h = lane >> 5, ql = lane & 31;
  // bijective XCD swizzle (512 % 8 == 0); each XCD gets 8 consecutive bh
  const int cpx = gridDim.x >> 3;
  const int wg = ((int)blockIdx.x & 7) * cpx + ((int)blockIdx.x >> 3);
  const int bh = wg >> 3;
  const int pi = wg & 7;                       // pair index 0..7
  const int b = bh >> 4, hd = bh & 15;
  const int panel = (wid < 4) ? (15 - pi) : pi;
  const int qw = panel * 128 + (wid & 3) * 32;
  const int qg = qw + ql;                      // this lane's q row
  const size_t rowbase = (size_t)b * S_ * D_ + (size_t)hd * DK_;
  const size_t vbase = (size_t)bh * 64 * S_;

  // Q fragments: B[q=qg][d = dstep*16 + h*8 .. +8]  (scaled by 0.125*log2e)
  bf16x8 aQ[4];
  {
    const short* qp = Qf + rowbase + (size_t)qg * D_ + h * 8;
#pragma unroll
    for (int d = 0; d < 4; ++d) aQ[d] = *(const bf16x8*)(qp + d * 16);
  }

  f32x16 o0, o1;  // O[d][q=qg]
#pragma unroll
  for (int i = 0; i < 16; ++i) { o0[i] = 0.f; o1[i] = 0.f; }
  float m_run = -1e30f, lsum = 0.f;

  // staging: wave stages rows [wid*8, wid*8+8) of K and V (1KB each).
  // LDS[r][c] = G[r][c ^ (r&7)] via pre-swizzled per-lane source.
  const int srow8 = lane >> 3;
  const int schunk = ((lane & 7) ^ srow8) * 8;
  const short* gK = Kf + rowbase + (size_t)(wid * 8 + srow8) * D_ + schunk;
  const short* gV = Vt + vbase + (size_t)(wid * 8 + srow8) * S_ + schunk;

  auto STAGE = [&](int bufi, int kt) {
    gload16(gK + (size_t)kt * D_, &sK[bufi][(wid * 8) * 64]);
    gload16(gV + kt, &sV[bufi][(wid * 8) * 64]);
  };

  const int nt = 32 - 2 * pi;  // hi panel tiles (covers lo panel's too)
  STAGE(0, 0);
  __syncthreads();
  int cur = 0;

  for (int t = 0; t < nt; ++t) {
    const int kt = t * 64;
    if (t + 1 < nt) STAGE(cur ^ 1, kt + 64);  // prefetch; drains at loop end
    if (kt <= qw + 31) {
      const short* bK = &sK[cur][0];
      const short* bV = &sV[cur][0];
      // ---- QK^T swapped: p = P[key][q=qg] ----
      f32x16 p0, p1;
#pragma unroll
      for (int i = 0; i < 16; ++i) { p0[i] = 0.f; p1[i] = 0.f; }
      __builtin_amdgcn_s_setprio(1);
#pragma unroll
      for (int d = 0; d < 4; ++d) {
        const int c = d * 2 + h;
        bf16x8 k0 = *(const bf16x8*)&bK[ql * 64 + ((c ^ (ql & 7)) << 3)];
        bf16x8 k1 = *(const bf16x8*)&bK[(32 + ql) * 64 + ((c ^ (ql & 7)) << 3)];
        p0 = __builtin_amdgcn_mfma_f32_32x32x16_bf16(k0, aQ[d], p0, 0, 0, 0);
        p1 = __builtin_amdgcn_mfma_f32_32x32x16_bf16(k1, aQ[d], p1, 0, 0, 0);
      }
      __builtin_amdgcn_s_setprio(0);
      // ---- causal mask (diagonal tiles only) ----
      if (kt + 63 > qw) {
        const int qk = qg - kt;
#pragma unroll
        for (int i = 0; i < 16; ++i) {
          const int k0i = 8 * (i >> 2) + 4 * h + (i & 3);
          if (k0i > qk) p0[i] = -1e30f;
          if (k0i + 32 > qk) p1[i] = -1e30f;
        }
      }
      // ---- online softmax (base-2), defer-max: rescale only if needed ----
      float mx = fmaxf(p0[0], p1[0]);
#pragma unroll
      for (int i = 1; i < 16; ++i) mx = fmaxf(mx, fmaxf(p0[i], p1[i]));
      mx = fmaxf(mx, __shfl_xor(mx, 32));
      if (mx > m_run + 8.f) {  // usually false after early tiles -> execz skip
        const float corr = exp2_hw(m_run - mx);
        m_run = mx;
        lsum *= corr;
#pragma unroll
        for (int i = 0; i < 16; ++i) { o0[i] *= corr; o1[i] *= corr; }
      }
      float rs = 0.f;
#pragma unroll
      for (int i = 0; i < 16; ++i) {
        p0[i] = exp2_hw(p0[i] - m_run); rs += p0[i];
        p1[i] = exp2_hw(p1[i] - m_run); rs += p1[i];
      }
      rs += __shfl_xor(rs, 32);
      lsum += rs;
      // ---- pack P to bf16 pairs ----
      uint32_t cj[8], dj[8];
#pragma unroll
      for (int j = 0; j < 4; ++j) {
        cj[j]     = cvtpk(p0[4 * j], p0[4 * j + 1]);
        dj[j]     = cvtpk(p0[4 * j + 2], p0[4 * j + 3]);
        cj[4 + j] = cvtpk(p1[4 * j], p1[4 * j + 1]);
        dj[4 + j] = cvtpk(p1[4 * j + 2], p1[4 * j + 3]);
      }
      // ---- PV swapped: B-frag[m] = P[qg][keys 16m+8h..+7] via xor-32 exchange
#pragma unroll
      for (int m = 0; m < 4; ++m) {
        const uint32_t pc = h ? cj[2 * m] : cj[2 * m + 1];
        const uint32_t pd = h ? dj[2 * m] : dj[2 * m + 1];
        const uint32_t rc = (uint32_t)__shfl_xor((int)pc, 32);
        const uint32_t rd = (uint32_t)__shfl_xor((int)pd, 32);
        union { uint32_t w[4]; bf16x8 v; } u;
        u.w[0] = h ? rc : cj[2 * m];
        u.w[1] = h ? rd : dj[2 * m];
        u.w[2] = h ? cj[2 * m + 1] : rc;
        u.w[3] = h ? dj[2 * m + 1] : rd;
        const int cv = m * 2 + h;
        bf16x8 v0 = *(const bf16x8*)&bV[ql * 64 + ((cv ^ (ql & 7)) << 3)];
        bf16x8 v1 = *(const bf16x8*)&bV[(32 + ql) * 64 + ((cv ^ (ql & 7)) << 3)];
        __builtin_amdgcn_s_setprio(1);
        o0 = __builtin_amdgcn_mfma_f32_32x32x16_bf16(v0, u.v, o0, 0, 0, 0);
        o1 = __builtin_amdgcn_mfma_f32_32x32x16_bf16(v1, u.v, o1, 0, 0, 0);
        __builtin_amdgcn_s_setprio(0);
      }
    }
    __syncthreads();  // drains vmcnt(0): tile t+1 landed; all done reading cur
    cur ^= 1;
  }

  // ---- epilogue: normalize, write bf16 rows ----
  const float invl = 1.f / lsum;
  short* op = AO + rowbase + (size_t)qg * D_;
#pragma unroll
  for (int j = 0; j < 4; ++j) {
    s16x4 w0, w1;
#pragma unroll
    for (int r = 0; r < 4; ++r) {
      w0[r] = f2bf(o0[4 * j + r] * invl);
      w1[r] = f2bf(o1[4 * j + r] * invl);
    }
    *(s16x4*)(op + 8 * j + 4 * h) = w0;
    *(s16x4*)(op + 32 + 8 * j + 4 * h) = w1;
  }
}

// ---------------- launch -------------------------------------------------------
extern "C" void kernel_launch(void* const* d_in, const int* in_sizes, int n_in,
                              void* d_out, int out_size, void* d_ws, size_t ws_size,
                              hipStream_t stream) {
  (void)in_sizes; (void)n_in; (void)out_size; (void)ws_size;
  const float* q  = (const float*)d_in[0];
  const float* k  = (const float*)d_in[1];
  const float* v  = (const float*)d_in[2];
  const float* Wq = (const float*)d_in[4];
  const float* bq = (const float*)d_in[5];
  const float* Wk = (const float*)d_in[6];
  const float* bk = (const float*)d_in[7];
  const float* Wv = (const float*)d_in[8];
  const float* bv = (const float*)d_in[9];
  const float* Wo = (const float*)d_in[10];
  const float* bo = (const float*)d_in[11];

  char* ws = (char*)d_ws;
  const size_t MB = 1ull << 20;
  short* wqb = (short*)(ws + 0 * MB);
  short* wkb = (short*)(ws + 2 * MB);
  short* wvb = (short*)(ws + 4 * MB);
  short* wob = (short*)(ws + 6 * MB);
  short* Qf  = (short*)(ws + 8 * MB);
  short* Kf  = (short*)(ws + 24 * MB);
  short* Vtb = (short*)(ws + 40 * MB);  // transposed V: [(b*1024+n)][s]
  short* xq  = (short*)(ws + 56 * MB);
  short* xk  = (short*)(ws + 72 * MB);
  short* xv  = (short*)(ws + 88 * MB);
  short* AO  = xq;

  const int BSD = B_ * S_ * D_;
  cvt_f32_bf16<<<4096, 256, 0, stream>>>(q, xq, BSD);
  cvt_f32_bf16<<<4096, 256, 0, stream>>>(k, xk, BSD);
  cvt_f32_bf16<<<4096, 256, 0, stream>>>(v, xv, BSD);
  cvt_f32_bf16<<<512, 256, 0, stream>>>(Wq, wqb, D_ * D_);
  cvt_f32_bf16<<<512, 256, 0, stream>>>(Wk, wkb, D_ * D_);
  cvt_f32_bf16<<<512, 256, 0, stream>>>(Wv, wvb, D_ * D_);
  cvt_f32_bf16<<<512, 256, 0, stream>>>(Wo, wob, D_ * D_);

  dim3 gg(M_ / 128, D_ / 128);
  // Q projection folds 1/sqrt(DK) * log2(e) so softmax runs in base-2
  gemm_bt<0><<<gg, 256, 0, stream>>>(xq, wqb, bq, Qf, D_, D_, 0.125f * 1.4426950408889634f);
  gemm_bt<0><<<gg, 256, 0, stream>>>(xk, wkb, bk, Kf, D_, D_, 1.0f);
  gemm_bt<2><<<gg, 256, 0, stream>>>(xv, wvb, bv, Vtb, D_, D_, 1.0f);

  attn_fwd<<<dim3(512), 512, 0, stream>>>(Qf, Kf, Vtb, AO);

  gemm_bt<1><<<gg, 256, 0, stream>>>(AO, wob, bo, d_out, D_, D_, 1.0f);
}